// Round 2
// baseline (3340.871 us; speedup 1.0000x reference)
//
#include <hip/hip_runtime.h>
#include <math.h>

#define SS 256      // sequence length S
#define BB 64       // batch B
#define EE 256      // embedding E
#define HD 256      // hidden per direction
#define G4 1024     // 4*HD
#define TT 16       // tags

__device__ __forceinline__ float sigm(float x) { return 1.0f / (1.0f + expf(-x)); }

// ---------------------------------------------------------------- init h + zero flags
// blocks 0..127: copy h0 -> hbuf parity0 ([dir][b][col]); blocks 128..135: zero flags
__global__ __launch_bounds__(256) void k_init(const float* __restrict__ h0,
                                              float* __restrict__ hbuf,
                                              int* __restrict__ flags) {
    int bid = blockIdx.x;
    if (bid < 128) {
        int i = bid * 256 + threadIdx.x;          // 32768 elements
        hbuf[i] = h0[i];                          // parity-0 = [dir][b][col]
    } else {
        int i = (bid - 128) * 256 + threadIdx.x;  // 2048 ints
        flags[i] = 0;
    }
}

// ---------------------------------------------------------------- input projection
// G_T[s][n(1024)][b(64)] = emb[token(s,b)] . W_ih[n] + (b_ih[n]+b_hh[n])
__global__ __launch_bounds__(256) void k_gemm_in(
    const int* __restrict__ token, const float* __restrict__ emb,
    const float* __restrict__ w_ih_f, const float* __restrict__ w_ih_b,
    const float* __restrict__ b_ih_f, const float* __restrict__ b_hh_f,
    const float* __restrict__ b_ih_b, const float* __restrict__ b_hh_b,
    float* __restrict__ GfT, float* __restrict__ GbT) {
    __shared__ float As[16][128];
    __shared__ float Bs[16][64];
    const int tid = threadIdx.x;
    const int m_base = blockIdx.x * 128;          // 128 rows (2 s-values)
    const int n_base = blockIdx.y * 64;
    const bool is_b = (n_base >= 1024);
    const float* W = is_b ? w_ih_b : w_ih_f;
    const int n_off = is_b ? (n_base - 1024) : n_base;

    // A staging: 256 threads -> 128 rows x 2 k-halves
    const int a_mi = tid & 127;
    const int a_k4 = tid >> 7;                    // 0/1 -> k offset 0/8
    const int m = m_base + a_mi;
    const int s_idx = m >> 6, b_idx = m & 63;
    const long emb_row = (long)token[b_idx * SS + s_idx] * EE;

    // B staging: 64 n x 4 k-groups
    const int b_n = tid & 63;
    const int b_k4 = tid >> 6;                    // 0..3 -> k offset *4
    const float* wrow = W + (long)(n_off + b_n) * EE;

    // compute mapping: tx (16) -> m interleaved, ty (16) -> 4 n each
    const int tx = tid & 15;
    const int ty = tid >> 4;
    float acc[8][4];
#pragma unroll
    for (int i = 0; i < 8; i++)
#pragma unroll
        for (int j = 0; j < 4; j++) acc[i][j] = 0.f;

    for (int kt = 0; kt < EE; kt += 16) {
        float4 av0 = *(const float4*)(emb + emb_row + kt + a_k4 * 8);
        float4 av1 = *(const float4*)(emb + emb_row + kt + a_k4 * 8 + 4);
        float4 bv  = *(const float4*)(wrow + kt + b_k4 * 4);
        __syncthreads();
        {
            int k0 = a_k4 * 8;
            As[k0 + 0][a_mi] = av0.x; As[k0 + 1][a_mi] = av0.y;
            As[k0 + 2][a_mi] = av0.z; As[k0 + 3][a_mi] = av0.w;
            As[k0 + 4][a_mi] = av1.x; As[k0 + 5][a_mi] = av1.y;
            As[k0 + 6][a_mi] = av1.z; As[k0 + 7][a_mi] = av1.w;
            int k1 = b_k4 * 4;
            Bs[k1 + 0][b_n] = bv.x; Bs[k1 + 1][b_n] = bv.y;
            Bs[k1 + 2][b_n] = bv.z; Bs[k1 + 3][b_n] = bv.w;
        }
        __syncthreads();
#pragma unroll
        for (int k = 0; k < 16; k++) {
            float am[8];
#pragma unroll
            for (int i = 0; i < 8; i++) am[i] = As[k][tx + 16 * i];
            float4 b0 = *(const float4*)&Bs[k][ty * 4];
            float bn[4] = {b0.x, b0.y, b0.z, b0.w};
#pragma unroll
            for (int i = 0; i < 8; i++)
#pragma unroll
                for (int j = 0; j < 4; j++)
                    acc[i][j] = fmaf(am[i], bn[j], acc[i][j]);
        }
    }
    const float* bi_p = is_b ? b_ih_b : b_ih_f;
    const float* bh_p = is_b ? b_hh_b : b_hh_f;
    float bb[4];
#pragma unroll
    for (int j = 0; j < 4; j++) {
        int n = n_off + ty * 4 + j;
        bb[j] = bi_p[n] + bh_p[n];
    }
    float* Gout = is_b ? GbT : GfT;
#pragma unroll
    for (int i = 0; i < 8; i++) {
        int mm = m_base + tx + 16 * i;
        int ss = mm >> 6, bbx = mm & 63;
#pragma unroll
        for (int j = 0; j < 4; j++) {
            long addr = ((long)ss * G4 + n_off + ty * 4 + j) * BB + bbx;
            Gout[addr] = acc[i][j] + bb[j];
        }
    }
}

// ---------------------------------------------------------------- persistent BiLSTM
// 128 wgs: dir = bid>>6, w = bid&63 owns h-cols [4w,4w+4). 512 thr: b=tid&63, q=tid>>6.
__global__ __launch_bounds__(512, 1) void k_lstm(
    const float* __restrict__ GfT, const float* __restrict__ GbT,
    const float* __restrict__ w_hh_f, const float* __restrict__ w_hh_b,
    const float* __restrict__ c0,
    float* __restrict__ hbuf, float* __restrict__ hcat,
    int* __restrict__ flags) {
    __shared__ float wsm[16][256];    // 16 (gate*4+col) rows x K=256
    __shared__ float pd[16 * 8 * 64]; // partials [p][q][b]
    __shared__ float cs[64 * 5];      // c-state [b][col] padded
    const int tid = threadIdx.x;
    const int w = blockIdx.x & 63;
    const int dir = blockIdx.x >> 6;
    const int colbase = w * 4;
    const float* whh = dir ? w_hh_b : w_hh_f;
    const float* GT = dir ? GbT : GfT;
    const int b = tid & 63;
    const int q = tid >> 6;           // 0..7 K-slice

    // load weight slice: wsm[p][k] = whh[(p>>2)*256 + colbase + (p&3)][k]
#pragma unroll
    for (int j = 0; j < 2; ++j) {
        int f = tid * 8 + j * 4;
        int p = f >> 8, k = f & 255;
        int row = (p >> 2) * HD + colbase + (p & 3);
        *(float4*)&wsm[p][k] = *(const float4*)(whh + (long)row * HD + k);
    }
    if (tid < 256) {
        int cc = tid >> 6;
        cs[b * 5 + cc] = c0[dir * (BB * HD) + b * HD + colbase + cc];
    }
    __syncthreads();

    int* myflag = flags + (dir * 64 + w) * 16;
    int* fl = flags + dir * 64 * 16;

    for (int s = 0; s < SS; ++s) {
        const int sidx = dir ? (SS - 1 - s) : s;
        const float* hp = hbuf + ((s & 1) * 2 + dir) * (BB * HD);
        float* hn = hbuf + (((s + 1) & 1) * 2 + dir) * (BB * HD);

        // prefetch G for the update phase (coalesced; independent of h)
        float gpre[4];
        if (tid < 256) {
            int cc = tid >> 6;
#pragma unroll
            for (int g = 0; g < 4; ++g)
                gpre[g] = GT[((long)sidx * G4 + g * HD + colbase + cc) * BB + b];
        }

        // partial dots over K-slice [32q, 32q+32)
        float pdc[16];
#pragma unroll
        for (int p = 0; p < 16; ++p) pdc[p] = 0.f;
        const float* hrow = hp + b * HD + q * 32;
#pragma unroll
        for (int k4 = 0; k4 < 32; k4 += 4) {
            float4 hv = *(const float4*)(hrow + k4);
#pragma unroll
            for (int p = 0; p < 16; ++p) {
                float4 wv = *(const float4*)&wsm[p][q * 32 + k4];
                pdc[p] = fmaf(hv.x, wv.x, fmaf(hv.y, wv.y,
                          fmaf(hv.z, wv.z, fmaf(hv.w, wv.w, pdc[p]))));
            }
        }
#pragma unroll
        for (int p = 0; p < 16; ++p) pd[(p * 8 + q) * 64 + b] = pdc[p];
        __syncthreads();

        if (tid < 256) {
            const int cc = tid >> 6;
            float gs[4];
#pragma unroll
            for (int g = 0; g < 4; ++g) {
                float acc = gpre[g];
#pragma unroll
                for (int qq = 0; qq < 8; ++qq)
                    acc += pd[((g * 4 + cc) * 8 + qq) * 64 + b];
                gs[g] = acc;
            }
            float ci = cs[b * 5 + cc];
            float cn = sigm(gs[1]) * ci + sigm(gs[0]) * tanhf(gs[2]);
            float hv = sigm(gs[3]) * tanhf(cn);
            cs[b * 5 + cc] = cn;
            hn[b * HD + colbase + cc] = hv;
            hcat[((long)sidx * BB + b) * (2 * HD) + dir * HD + colbase + cc] = hv;
        }
        __syncthreads();   // drains h stores (waitcnt before barrier)

        if (s < SS - 1) {
            if (tid < 64) {
                if (tid == 0)
                    __hip_atomic_store(myflag, s + 1, __ATOMIC_RELEASE,
                                       __HIP_MEMORY_SCOPE_AGENT);
                int budget = 1 << 14;
                for (;;) {
                    int v = __hip_atomic_load(fl + tid * 16, __ATOMIC_ACQUIRE,
                                              __HIP_MEMORY_SCOPE_AGENT);
                    if (__all(v >= s + 1) || --budget <= 0) break;
                    __builtin_amdgcn_s_sleep(2);
                }
            }
            __syncthreads();
        }
    }
}

// ---------------------------------------------------------------- tag projection
__global__ __launch_bounds__(256) void k_feats(const float* __restrict__ hcat,
                                               const float* __restrict__ W_tag,
                                               const float* __restrict__ b_tag,
                                               float* __restrict__ feats) {
    int tid = threadIdx.x;
    int n = tid & 15, mi = tid >> 4;
    long m = (long)blockIdx.x * 16 + mi;
    const float* hr = hcat + m * 512;
    const float* wr = W_tag + n * 512;
    float acc = 0.f;
#pragma unroll 4
    for (int k = 0; k < 512; k += 4) {
        float4 h = *(const float4*)(hr + k);
        float4 w = *(const float4*)(wr + k);
        acc = fmaf(h.x, w.x, fmaf(h.y, w.y, fmaf(h.z, w.z, fmaf(h.w, w.w, acc))));
    }
    feats[m * TT + n] = acc + b_tag[n];
}

// ---------------------------------------------------------------- Viterbi + backtrack
__global__ __launch_bounds__(64) void k_viterbi(const float* __restrict__ feats,
                                                const float* __restrict__ trans,
                                                int* __restrict__ out) {
    __shared__ float tr[16][17];
    __shared__ float fv[2][4][16];
    __shared__ unsigned char bp[4][256][16];
    const int lane = threadIdx.x;
    const int bi = lane >> 4, nx = lane & 15;
    const int b = blockIdx.x * 4 + bi;

    for (int i = lane; i < 256; i += 64) tr[i >> 4][i & 15] = trans[i];
    fv[0][bi][nx] = (nx == 14) ? 0.f : -10000.f;   // START = 14
    __syncthreads();

    int cur = 0;
    for (int s = 0; s < SS; s++) {
        float fe = feats[((long)s * BB + b) * TT + nx];
        float best = -3.4e38f;
        int bestp = 0;
#pragma unroll
        for (int p = 0; p < 16; p++) {
            float sc = (fv[cur][bi][p] + tr[nx][p]) + fe;  // ref op order
            if (sc > best) { best = sc; bestp = p; }       // first-max wins
        }
        fv[cur ^ 1][bi][nx] = best;
        bp[bi][s][nx] = (unsigned char)bestp;
        __syncthreads();
        cur ^= 1;
    }
    float bv = fv[cur][bi][nx] + tr[15][nx];       // STOP = 15
    int bidx = nx;
#pragma unroll
    for (int off = 1; off < 16; off <<= 1) {       // stays within 16-lane group
        float ov = __shfl_xor(bv, off, 64);
        int oi = __shfl_xor(bidx, off, 64);
        if (ov > bv || (ov == bv && oi < bidx)) { bv = ov; bidx = oi; }
    }
    if (nx == 0) {
        int tag = bidx;
        for (int s = SS - 1; s > 0; --s) {
            out[b * SS + s] = tag;
            tag = bp[bi][s][tag];
        }
        out[b * SS] = tag;
    }
}

// ---------------------------------------------------------------- launcher
extern "C" void kernel_launch(void* const* d_in, const int* in_sizes, int n_in,
                              void* d_out, int out_size, void* d_ws, size_t ws_size,
                              hipStream_t stream) {
    const int*   token  = (const int*)  d_in[0];
    const float* emb    = (const float*)d_in[1];
    const float* w_ih_f = (const float*)d_in[2];
    const float* w_hh_f = (const float*)d_in[3];
    const float* b_ih_f = (const float*)d_in[4];
    const float* b_hh_f = (const float*)d_in[5];
    const float* w_ih_b = (const float*)d_in[6];
    const float* w_hh_b = (const float*)d_in[7];
    const float* b_ih_b = (const float*)d_in[8];
    const float* b_hh_b = (const float*)d_in[9];
    const float* W_tag  = (const float*)d_in[10];
    const float* b_tag  = (const float*)d_in[11];
    const float* trans  = (const float*)d_in[12];
    const float* h0     = (const float*)d_in[13];
    const float* c0     = (const float*)d_in[14];
    int* out = (int*)d_out;

    char* ws = (char*)d_ws;
    float* GfT   = (float*)(ws);                                   // 64 MiB
    float* GbT   = (float*)(ws + ((size_t)64 << 20));              // 64 MiB
    float* hcat  = (float*)(ws + ((size_t)128 << 20));             // 32 MiB
    float* feats = (float*)(ws + ((size_t)160 << 20));             // 1 MiB
    float* hbuf  = (float*)(ws + ((size_t)161 << 20));             // 256 KiB
    int*   flags = (int*)  (ws + ((size_t)161 << 20) + (256 << 10)); // 8 KiB

    k_init<<<dim3(136), dim3(256), 0, stream>>>(h0, hbuf, flags);
    k_gemm_in<<<dim3(128, 32), dim3(256), 0, stream>>>(
        token, emb, w_ih_f, w_ih_b, b_ih_f, b_hh_f, b_ih_b, b_hh_b, GfT, GbT);
    k_lstm<<<dim3(128), dim3(512), 0, stream>>>(
        GfT, GbT, w_hh_f, w_hh_b, c0, hbuf, hcat, flags);
    k_feats<<<dim3(1024), dim3(256), 0, stream>>>(hcat, W_tag, b_tag, feats);
    k_viterbi<<<dim3(16), dim3(64), 0, stream>>>(feats, trans, out);
}